// Round 12
// baseline (361.111 us; speedup 1.0000x reference)
//
#include <hip/hip_runtime.h>

#define N 8192
#define DIM 128
#define NCHUNK 128           // j-chunks in pass 1 -> partial[NCHUNK][N]
#define JTILE (N / NCHUNK)   // 64 j per pass-1 block

typedef float f32x4 __attribute__((ext_vector_type(4)));
typedef float f32x2 __attribute__((ext_vector_type(2)));

// ---------------------------------------------------------------------------
// Pass 0: encoder MLP. 128 -> 64 -> 32 -> 16 -> 16, relu on first three.
// R7 verbatim (measured-good): TWO threads per row (t&31 = row, t>>5 =
// output-half), 256 blocks x 64 threads -> one wave on EVERY CU. Cross-half
// activation exchange via LDS; block = one wave, so LDS program order makes
// write-before-read safe.
// ---------------------------------------------------------------------------
__global__ __launch_bounds__(64) void encoder_kernel(
    const float* __restrict__ x,
    const float* __restrict__ W1, const float* __restrict__ b1,
    const float* __restrict__ W2, const float* __restrict__ b2,
    const float* __restrict__ W3, const float* __restrict__ b3,
    const float* __restrict__ W4, const float* __restrict__ b4,
    float* __restrict__ z, float* __restrict__ zT, float* __restrict__ sqout)
{
    __shared__ float sW1[128 * 64];
    __shared__ float sW2[64 * 32];
    __shared__ float sW3[32 * 16];
    __shared__ float sW4[16 * 16];
    __shared__ float sb1[64];
    __shared__ float sb2[32];
    __shared__ float sb3[16];
    __shared__ float sb4[16];
    __shared__ float sh1[32 * 65];   // 32 rows, stride 65: conflict-light
    __shared__ float sh2[32 * 33];
    __shared__ float sh3[32 * 17];

    int t = threadIdx.x;
    int r = t & 31;    // local row
    int h = t >> 5;    // output half (0/1)

    for (int idx = t; idx < 128 * 64; idx += 64) sW1[idx] = W1[idx];
    for (int idx = t; idx < 64 * 32; idx += 64) sW2[idx] = W2[idx];
    for (int idx = t; idx < 32 * 16; idx += 64) sW3[idx] = W3[idx];
    for (int idx = t; idx < 16 * 16; idx += 64) sW4[idx] = W4[idx];
    sb1[t] = b1[t];
    if (t < 32) sb2[t] = b2[t];
    if (t < 16) { sb3[t] = b3[t]; sb4[t] = b4[t]; }
    __syncthreads();

    int row = blockIdx.x * 32 + r;
    const float4* xr = (const float4*)(x + (size_t)row * DIM);

    // ---- layer 1: 128 -> 64, this thread computes outputs [h*32, h*32+32) ----
    float h1[32];
    #pragma unroll
    for (int k = 0; k < 32; ++k) h1[k] = sb1[h * 32 + k];
    for (int j4 = 0; j4 < 32; ++j4) {
        float4 xv = xr[j4];
        const float* w0 = &sW1[(j4 * 4 + 0) * 64 + h * 32];
        const float* w1 = &sW1[(j4 * 4 + 1) * 64 + h * 32];
        const float* w2 = &sW1[(j4 * 4 + 2) * 64 + h * 32];
        const float* w3 = &sW1[(j4 * 4 + 3) * 64 + h * 32];
        #pragma unroll
        for (int k = 0; k < 32; ++k) h1[k] = fmaf(xv.x, w0[k], h1[k]);
        #pragma unroll
        for (int k = 0; k < 32; ++k) h1[k] = fmaf(xv.y, w1[k], h1[k]);
        #pragma unroll
        for (int k = 0; k < 32; ++k) h1[k] = fmaf(xv.z, w2[k], h1[k]);
        #pragma unroll
        for (int k = 0; k < 32; ++k) h1[k] = fmaf(xv.w, w3[k], h1[k]);
    }
    #pragma unroll
    for (int k = 0; k < 32; ++k) sh1[r * 65 + h * 32 + k] = fmaxf(h1[k], 0.0f);

    // ---- layer 2: 64 -> 32, outputs [h*16, h*16+16), inputs all 64 ----
    float h2[16];
    #pragma unroll
    for (int k = 0; k < 16; ++k) h2[k] = sb2[h * 16 + k];
    for (int j = 0; j < 64; ++j) {
        float a = sh1[r * 65 + j];
        #pragma unroll
        for (int k = 0; k < 16; ++k) h2[k] = fmaf(a, sW2[j * 32 + h * 16 + k], h2[k]);
    }
    #pragma unroll
    for (int k = 0; k < 16; ++k) sh2[r * 33 + h * 16 + k] = fmaxf(h2[k], 0.0f);

    // ---- layer 3: 32 -> 16, outputs [h*8, h*8+8) ----
    float h3[8];
    #pragma unroll
    for (int k = 0; k < 8; ++k) h3[k] = sb3[h * 8 + k];
    for (int j = 0; j < 32; ++j) {
        float a = sh2[r * 33 + j];
        #pragma unroll
        for (int k = 0; k < 8; ++k) h3[k] = fmaf(a, sW3[j * 16 + h * 8 + k], h3[k]);
    }
    #pragma unroll
    for (int k = 0; k < 8; ++k) sh3[r * 17 + h * 8 + k] = fmaxf(h3[k], 0.0f);

    // ---- layer 4: 16 -> 16, no relu, outputs [h*8, h*8+8) ----
    float zo[8];
    #pragma unroll
    for (int k = 0; k < 8; ++k) zo[k] = sb4[h * 8 + k];
    for (int j = 0; j < 16; ++j) {
        float a = sh3[r * 17 + j];
        #pragma unroll
        for (int k = 0; k < 8; ++k) zo[k] = fmaf(a, sW4[j * 16 + h * 8 + k], zo[k]);
    }

    float s = 0.0f;
    #pragma unroll
    for (int k = 0; k < 8; ++k) s = fmaf(zo[k], zo[k], s);
    s += __shfl_xor(s, 32, 64);          // combine the two halves' partial sums
    if (h == 0) sqout[row] = s;
    float4* zr = (float4*)(z + (size_t)row * 16 + h * 8);
    zr[0] = make_float4(zo[0], zo[1], zo[2], zo[3]);
    zr[1] = make_float4(zo[4], zo[5], zo[6], zo[7]);
    // transposed copy: for fixed k, 32 lanes store 32 consecutive rows
    #pragma unroll
    for (int k = 0; k < 8; ++k) zT[(size_t)(h * 8 + k) * N + row] = zo[k];
}

// ---------------------------------------------------------------------------
// Pass 1: row sums of numerator = 1/(1+dist). v5 (the ONLY change vs the
// 357.0-us R11 config): NCHUNK 64 -> 128, grid (16,128) = 2048 blocks = 8
// blocks/CU = 8 waves/SIMD (was 4). R11 confirmed pass1 is DS-broadcast-
// latency-bound (4 waves/SIMD beat 2 by the predicted margin); this probes
// whether exposed latency remains at 4. Total staging traffic unchanged
// (grid.x still 16). Staging: 256 threads x 1 float4 = the whole 64-row
// tile in one instruction per thread.
// ---------------------------------------------------------------------------
__global__ __launch_bounds__(256) void pass1_kernel(
    const float* __restrict__ z, const float* __restrict__ sq,
    float* __restrict__ partial)
{
    __shared__ float s_zj[JTILE * 16];
    __shared__ float s_sqj[JTILE];

    int t = threadIdx.x;
    int i0 = blockIdx.x * 256 + t;      // 0..4095
    int i1 = i0 + 4096;
    int jb = blockIdx.y * JTILE;

    // stage z tile for this block's 64-j range: thread t copies float4 #t
    {
        const float4* src = (const float4*)(z + (size_t)jb * 16);
        ((float4*)s_zj)[t] = src[t];
        if (t < JTILE) s_sqj[t] = sq[jb + t];
    }

    f32x2 zi0[8], zi1[8];
    {
        const float4* p0 = (const float4*)(z + (size_t)i0 * 16);
        const float4* p1 = (const float4*)(z + (size_t)i1 * 16);
        #pragma unroll
        for (int q = 0; q < 4; ++q) {
            float4 v0 = p0[q]; float4 v1 = p1[q];
            zi0[2*q]   = f32x2{v0.x, v0.y}; zi0[2*q+1] = f32x2{v0.z, v0.w};
            zi1[2*q]   = f32x2{v1.x, v1.y}; zi1[2*q+1] = f32x2{v1.z, v1.w};
        }
    }
    float sqi0p = 1.0f + sq[i0], sqi1p = 1.0f + sq[i1];
    __syncthreads();

    float acc0 = 0.0f, acc1 = 0.0f;
    #pragma unroll 4
    for (int jj = 0; jj < JTILE; ++jj) {
        const float4* zj4 = (const float4*)(s_zj + jj * 16);
        f32x2 d0 = {0.0f, 0.0f}, d1 = {0.0f, 0.0f};
        #pragma unroll
        for (int q = 0; q < 4; ++q) {
            float4 v = zj4[q];                 // ds_read_b128 broadcast
            f32x2 wa = {v.x, v.y}, wb = {v.z, v.w};
            d0 += zi0[2*q] * wa;
            d0 += zi0[2*q+1] * wb;
            d1 += zi1[2*q] * wa;
            d1 += zi1[2*q+1] * wb;
        }
        float s0 = d0.x + d0.y, s1 = d1.x + d1.y;
        float sj = s_sqj[jj];
        // dist+1 = max((1+sqi)+sj - 2*dot, 1): exact (max(a,0)+1 == max(a+1,1))
        acc0 += __builtin_amdgcn_rcpf(fmaxf(fmaf(-2.0f, s0, sqi0p + sj), 1.0f));
        acc1 += __builtin_amdgcn_rcpf(fmaxf(fmaf(-2.0f, s1, sqi1p + sj), 1.0f));
    }
    partial[blockIdx.y * N + i0] = acc0;
    partial[blockIdx.y * N + i1] = acc1;
}

// ---------------------------------------------------------------------------
// Pass 2: recompute numerators, scale by 1/rowsum, stream to out.
// R3 sweep verbatim, 4 i-rows per block, grid 2048 (LOCKED: R6 measured
// 8-row at +7 us -> pass2 is HBM-store/latency-bound). Prologue: each lane
// sums 2 of the NCHUNK=128 partials, then the 64-lane tree.
// ---------------------------------------------------------------------------
__global__ __launch_bounds__(256) void pass2_kernel(
    const float* __restrict__ z, const float* __restrict__ zT,
    const float* __restrict__ sq,
    const float* __restrict__ partial, float* __restrict__ out)
{
    __shared__ float s_inv[4];

    int t = threadIdx.x;
    int ibase = blockIdx.x * 4;
    int w = t >> 6, lane = t & 63;

    // rowsum: wave w reduces the NCHUNK=128 partials of row ibase+w
    {
        float v = partial[(size_t)lane * N + ibase + w]
                + partial[(size_t)(lane + 64) * N + ibase + w];
        #pragma unroll
        for (int off = 32; off > 0; off >>= 1) v += __shfl_xor(v, off, 64);
        if (lane == 0) s_inv[w] = 1.0f / v;
    }

    float zi[4][16];
    float sqi[4];
    #pragma unroll
    for (int rr = 0; rr < 4; ++rr) {
        const float4* p = (const float4*)(z + (size_t)(ibase + rr) * 16);
        #pragma unroll
        for (int q = 0; q < 4; ++q) {
            float4 v = p[q];
            zi[rr][4*q]   = v.x; zi[rr][4*q+1] = v.y;
            zi[rr][4*q+2] = v.z; zi[rr][4*q+3] = v.w;
        }
        sqi[rr] = sq[ibase + rr];
    }
    __syncthreads();
    float inv[4];
    #pragma unroll
    for (int rr = 0; rr < 4; ++rr) inv[rr] = s_inv[rr];

    for (int jb = 0; jb < N; jb += 1024) {
        int j0 = jb + t * 4;
        // 16 contiguous 1-KB wave loads: zjT[k] = z^T[k][j0..j0+3]
        f32x4 zjT[16];
        #pragma unroll
        for (int k = 0; k < 16; ++k)
            zjT[k] = *(const f32x4*)(zT + (size_t)k * N + j0);
        f32x4 sqj = *(const f32x4*)(sq + j0);

        #pragma unroll
        for (int rr = 0; rr < 4; ++rr) {
            f32x4 d = {0.0f, 0.0f, 0.0f, 0.0f};
            #pragma unroll
            for (int k = 0; k < 16; ++k) d += zi[rr][k] * zjT[k];
            f32x4 dist = sqi[rr] + sqj - 2.0f * d;
            f32x4 num;
            num.x = __builtin_amdgcn_rcpf(1.0f + fmaxf(dist.x, 0.0f)) * inv[rr];
            num.y = __builtin_amdgcn_rcpf(1.0f + fmaxf(dist.y, 0.0f)) * inv[rr];
            num.z = __builtin_amdgcn_rcpf(1.0f + fmaxf(dist.z, 0.0f)) * inv[rr];
            num.w = __builtin_amdgcn_rcpf(1.0f + fmaxf(dist.w, 0.0f)) * inv[rr];
            __builtin_nontemporal_store(num,
                (f32x4*)(out + (size_t)(ibase + rr) * N + j0));
        }
    }
}

extern "C" void kernel_launch(void* const* d_in, const int* in_sizes, int n_in,
                              void* d_out, int out_size, void* d_ws, size_t ws_size,
                              hipStream_t stream) {
    const float* x  = (const float*)d_in[0];
    const float* W1 = (const float*)d_in[1];
    const float* b1 = (const float*)d_in[2];
    const float* W2 = (const float*)d_in[3];
    const float* b2 = (const float*)d_in[4];
    const float* W3 = (const float*)d_in[5];
    const float* b3 = (const float*)d_in[6];
    const float* W4 = (const float*)d_in[7];
    const float* b4 = (const float*)d_in[8];
    float* out = (float*)d_out;

    float* ws = (float*)d_ws;
    float* z       = ws;                        // N*16     = 131072 floats
    float* zT      = ws + N * 16;               // 16*N     = 131072 floats
    float* sqv     = ws + N * 32;               // N        =   8192 floats
    float* partial = ws + N * 32 + N;           // NCHUNK*N = 1048576 floats
    // total ws usage: 1318912 floats = 5.03 MiB (ws is ~1 GiB per the poison fill)

    encoder_kernel<<<256, 64, 0, stream>>>(x, W1, b1, W2, b2, W3, b3, W4, b4, z, zT, sqv);
    pass1_kernel<<<dim3(16, NCHUNK), 256, 0, stream>>>(z, sqv, partial);
    pass2_kernel<<<N / 4, 256, 0, stream>>>(z, zT, sqv, partial, out);
}

// Round 13
// 356.501 us; speedup vs baseline: 1.0129x; 1.0129x over previous
//
#include <hip/hip_runtime.h>

#define N 8192
#define DIM 128
#define NCHUNK 64            // j-chunks in pass 1 -> partial[NCHUNK][N]
#define JTILE (N / NCHUNK)   // 128 j per pass-1 block

typedef float f32x4 __attribute__((ext_vector_type(4)));
typedef float f32x2 __attribute__((ext_vector_type(2)));

// ---------------------------------------------------------------------------
// FINAL CONFIG (best measured: 357.0 us, R11). Occupancy curve for pass1:
// 2 waves/SIMD = 360.6, 4 = 357.0, 8 = 361.1 -> locked at 4 (NCHUNK=64).
// pass2 row-tile curve: 4 rows = best (R3), 8 rows = +7 (R6). Encoder:
// 2-thread/row all-CU = -15 vs 1-thread/row (R7).
// ---------------------------------------------------------------------------

// ---------------------------------------------------------------------------
// Pass 0: encoder MLP. 128 -> 64 -> 32 -> 16 -> 16, relu on first three.
// R7 verbatim: TWO threads per row (t&31 = row, t>>5 = output-half), 256
// blocks x 64 threads -> one wave on EVERY CU. Cross-half activation
// exchange via LDS; block = one wave, so LDS program order makes
// write-before-read safe.
// ---------------------------------------------------------------------------
__global__ __launch_bounds__(64) void encoder_kernel(
    const float* __restrict__ x,
    const float* __restrict__ W1, const float* __restrict__ b1,
    const float* __restrict__ W2, const float* __restrict__ b2,
    const float* __restrict__ W3, const float* __restrict__ b3,
    const float* __restrict__ W4, const float* __restrict__ b4,
    float* __restrict__ z, float* __restrict__ zT, float* __restrict__ sqout)
{
    __shared__ float sW1[128 * 64];
    __shared__ float sW2[64 * 32];
    __shared__ float sW3[32 * 16];
    __shared__ float sW4[16 * 16];
    __shared__ float sb1[64];
    __shared__ float sb2[32];
    __shared__ float sb3[16];
    __shared__ float sb4[16];
    __shared__ float sh1[32 * 65];   // 32 rows, stride 65: conflict-light
    __shared__ float sh2[32 * 33];
    __shared__ float sh3[32 * 17];

    int t = threadIdx.x;
    int r = t & 31;    // local row
    int h = t >> 5;    // output half (0/1)

    for (int idx = t; idx < 128 * 64; idx += 64) sW1[idx] = W1[idx];
    for (int idx = t; idx < 64 * 32; idx += 64) sW2[idx] = W2[idx];
    for (int idx = t; idx < 32 * 16; idx += 64) sW3[idx] = W3[idx];
    for (int idx = t; idx < 16 * 16; idx += 64) sW4[idx] = W4[idx];
    sb1[t] = b1[t];
    if (t < 32) sb2[t] = b2[t];
    if (t < 16) { sb3[t] = b3[t]; sb4[t] = b4[t]; }
    __syncthreads();

    int row = blockIdx.x * 32 + r;
    const float4* xr = (const float4*)(x + (size_t)row * DIM);

    // ---- layer 1: 128 -> 64, this thread computes outputs [h*32, h*32+32) ----
    float h1[32];
    #pragma unroll
    for (int k = 0; k < 32; ++k) h1[k] = sb1[h * 32 + k];
    for (int j4 = 0; j4 < 32; ++j4) {
        float4 xv = xr[j4];
        const float* w0 = &sW1[(j4 * 4 + 0) * 64 + h * 32];
        const float* w1 = &sW1[(j4 * 4 + 1) * 64 + h * 32];
        const float* w2 = &sW1[(j4 * 4 + 2) * 64 + h * 32];
        const float* w3 = &sW1[(j4 * 4 + 3) * 64 + h * 32];
        #pragma unroll
        for (int k = 0; k < 32; ++k) h1[k] = fmaf(xv.x, w0[k], h1[k]);
        #pragma unroll
        for (int k = 0; k < 32; ++k) h1[k] = fmaf(xv.y, w1[k], h1[k]);
        #pragma unroll
        for (int k = 0; k < 32; ++k) h1[k] = fmaf(xv.z, w2[k], h1[k]);
        #pragma unroll
        for (int k = 0; k < 32; ++k) h1[k] = fmaf(xv.w, w3[k], h1[k]);
    }
    #pragma unroll
    for (int k = 0; k < 32; ++k) sh1[r * 65 + h * 32 + k] = fmaxf(h1[k], 0.0f);

    // ---- layer 2: 64 -> 32, outputs [h*16, h*16+16), inputs all 64 ----
    float h2[16];
    #pragma unroll
    for (int k = 0; k < 16; ++k) h2[k] = sb2[h * 16 + k];
    for (int j = 0; j < 64; ++j) {
        float a = sh1[r * 65 + j];
        #pragma unroll
        for (int k = 0; k < 16; ++k) h2[k] = fmaf(a, sW2[j * 32 + h * 16 + k], h2[k]);
    }
    #pragma unroll
    for (int k = 0; k < 16; ++k) sh2[r * 33 + h * 16 + k] = fmaxf(h2[k], 0.0f);

    // ---- layer 3: 32 -> 16, outputs [h*8, h*8+8) ----
    float h3[8];
    #pragma unroll
    for (int k = 0; k < 8; ++k) h3[k] = sb3[h * 8 + k];
    for (int j = 0; j < 32; ++j) {
        float a = sh2[r * 33 + j];
        #pragma unroll
        for (int k = 0; k < 8; ++k) h3[k] = fmaf(a, sW3[j * 16 + h * 8 + k], h3[k]);
    }
    #pragma unroll
    for (int k = 0; k < 8; ++k) sh3[r * 17 + h * 8 + k] = fmaxf(h3[k], 0.0f);

    // ---- layer 4: 16 -> 16, no relu, outputs [h*8, h*8+8) ----
    float zo[8];
    #pragma unroll
    for (int k = 0; k < 8; ++k) zo[k] = sb4[h * 8 + k];
    for (int j = 0; j < 16; ++j) {
        float a = sh3[r * 17 + j];
        #pragma unroll
        for (int k = 0; k < 8; ++k) zo[k] = fmaf(a, sW4[j * 16 + h * 8 + k], zo[k]);
    }

    float s = 0.0f;
    #pragma unroll
    for (int k = 0; k < 8; ++k) s = fmaf(zo[k], zo[k], s);
    s += __shfl_xor(s, 32, 64);          // combine the two halves' partial sums
    if (h == 0) sqout[row] = s;
    float4* zr = (float4*)(z + (size_t)row * 16 + h * 8);
    zr[0] = make_float4(zo[0], zo[1], zo[2], zo[3]);
    zr[1] = make_float4(zo[4], zo[5], zo[6], zo[7]);
    // transposed copy: for fixed k, 32 lanes store 32 consecutive rows
    #pragma unroll
    for (int k = 0; k < 8; ++k) zT[(size_t)(h * 8 + k) * N + row] = zo[k];
}

// ---------------------------------------------------------------------------
// Pass 1: row sums of numerator = 1/(1+dist). R11 verbatim (best: 357.0 us).
// NCHUNK=64, grid (16,64) = 1024 blocks = 4 waves/SIMD -- the measured
// optimum of the occupancy curve (2:360.6, 4:357.0, 8:361.1). Inner f32x2
// dot + exact max(a,0)+1 == max(a+1,1) fold.
// ---------------------------------------------------------------------------
__global__ __launch_bounds__(256) void pass1_kernel(
    const float* __restrict__ z, const float* __restrict__ sq,
    float* __restrict__ partial)
{
    __shared__ float s_zj[JTILE * 16];
    __shared__ float s_sqj[JTILE];

    int t = threadIdx.x;
    int i0 = blockIdx.x * 256 + t;      // 0..4095
    int i1 = i0 + 4096;
    int jb = blockIdx.y * JTILE;

    // stage z tile for this block's 128-j range: thread t copies half of
    // row jb + (t>>1) (two float4s); consecutive t -> consecutive 32B chunks
    {
        int jr = t >> 1, q2 = (t & 1) * 2;
        const float4* src = (const float4*)(z + (size_t)(jb + jr) * 16);
        float4* dst = (float4*)(s_zj + jr * 16);
        dst[q2]     = src[q2];
        dst[q2 + 1] = src[q2 + 1];
        if (t < JTILE) s_sqj[t] = sq[jb + t];
    }

    f32x2 zi0[8], zi1[8];
    {
        const float4* p0 = (const float4*)(z + (size_t)i0 * 16);
        const float4* p1 = (const float4*)(z + (size_t)i1 * 16);
        #pragma unroll
        for (int q = 0; q < 4; ++q) {
            float4 v0 = p0[q]; float4 v1 = p1[q];
            zi0[2*q]   = f32x2{v0.x, v0.y}; zi0[2*q+1] = f32x2{v0.z, v0.w};
            zi1[2*q]   = f32x2{v1.x, v1.y}; zi1[2*q+1] = f32x2{v1.z, v1.w};
        }
    }
    float sqi0p = 1.0f + sq[i0], sqi1p = 1.0f + sq[i1];
    __syncthreads();

    float acc0 = 0.0f, acc1 = 0.0f;
    #pragma unroll 4
    for (int jj = 0; jj < JTILE; ++jj) {
        const float4* zj4 = (const float4*)(s_zj + jj * 16);
        f32x2 d0 = {0.0f, 0.0f}, d1 = {0.0f, 0.0f};
        #pragma unroll
        for (int q = 0; q < 4; ++q) {
            float4 v = zj4[q];                 // ds_read_b128 broadcast
            f32x2 wa = {v.x, v.y}, wb = {v.z, v.w};
            d0 += zi0[2*q] * wa;
            d0 += zi0[2*q+1] * wb;
            d1 += zi1[2*q] * wa;
            d1 += zi1[2*q+1] * wb;
        }
        float s0 = d0.x + d0.y, s1 = d1.x + d1.y;
        float sj = s_sqj[jj];
        // dist+1 = max((1+sqi)+sj - 2*dot, 1): exact (max(a,0)+1 == max(a+1,1))
        acc0 += __builtin_amdgcn_rcpf(fmaxf(fmaf(-2.0f, s0, sqi0p + sj), 1.0f));
        acc1 += __builtin_amdgcn_rcpf(fmaxf(fmaf(-2.0f, s1, sqi1p + sj), 1.0f));
    }
    partial[blockIdx.y * N + i0] = acc0;
    partial[blockIdx.y * N + i1] = acc1;
}

// ---------------------------------------------------------------------------
// Pass 2: recompute numerators, scale by 1/rowsum, stream to out.
// R3 sweep verbatim, 4 i-rows per block, grid 2048 (LOCKED: R6 measured
// 8-row at +7 us -> pass2 is HBM-store/latency-bound). Prologue reduction
// over the full 64-lane wave for NCHUNK=64.
// ---------------------------------------------------------------------------
__global__ __launch_bounds__(256) void pass2_kernel(
    const float* __restrict__ z, const float* __restrict__ zT,
    const float* __restrict__ sq,
    const float* __restrict__ partial, float* __restrict__ out)
{
    __shared__ float s_inv[4];

    int t = threadIdx.x;
    int ibase = blockIdx.x * 4;
    int w = t >> 6, lane = t & 63;

    // rowsum: wave w reduces the NCHUNK=64 partials of row ibase+w
    {
        float v = partial[(size_t)lane * N + ibase + w];
        #pragma unroll
        for (int off = 32; off > 0; off >>= 1) v += __shfl_xor(v, off, 64);
        if (lane == 0) s_inv[w] = 1.0f / v;
    }

    float zi[4][16];
    float sqi[4];
    #pragma unroll
    for (int rr = 0; rr < 4; ++rr) {
        const float4* p = (const float4*)(z + (size_t)(ibase + rr) * 16);
        #pragma unroll
        for (int q = 0; q < 4; ++q) {
            float4 v = p[q];
            zi[rr][4*q]   = v.x; zi[rr][4*q+1] = v.y;
            zi[rr][4*q+2] = v.z; zi[rr][4*q+3] = v.w;
        }
        sqi[rr] = sq[ibase + rr];
    }
    __syncthreads();
    float inv[4];
    #pragma unroll
    for (int rr = 0; rr < 4; ++rr) inv[rr] = s_inv[rr];

    for (int jb = 0; jb < N; jb += 1024) {
        int j0 = jb + t * 4;
        // 16 contiguous 1-KB wave loads: zjT[k] = z^T[k][j0..j0+3]
        f32x4 zjT[16];
        #pragma unroll
        for (int k = 0; k < 16; ++k)
            zjT[k] = *(const f32x4*)(zT + (size_t)k * N + j0);
        f32x4 sqj = *(const f32x4*)(sq + j0);

        #pragma unroll
        for (int rr = 0; rr < 4; ++rr) {
            f32x4 d = {0.0f, 0.0f, 0.0f, 0.0f};
            #pragma unroll
            for (int k = 0; k < 16; ++k) d += zi[rr][k] * zjT[k];
            f32x4 dist = sqi[rr] + sqj - 2.0f * d;
            f32x4 num;
            num.x = __builtin_amdgcn_rcpf(1.0f + fmaxf(dist.x, 0.0f)) * inv[rr];
            num.y = __builtin_amdgcn_rcpf(1.0f + fmaxf(dist.y, 0.0f)) * inv[rr];
            num.z = __builtin_amdgcn_rcpf(1.0f + fmaxf(dist.z, 0.0f)) * inv[rr];
            num.w = __builtin_amdgcn_rcpf(1.0f + fmaxf(dist.w, 0.0f)) * inv[rr];
            __builtin_nontemporal_store(num,
                (f32x4*)(out + (size_t)(ibase + rr) * N + j0));
        }
    }
}

extern "C" void kernel_launch(void* const* d_in, const int* in_sizes, int n_in,
                              void* d_out, int out_size, void* d_ws, size_t ws_size,
                              hipStream_t stream) {
    const float* x  = (const float*)d_in[0];
    const float* W1 = (const float*)d_in[1];
    const float* b1 = (const float*)d_in[2];
    const float* W2 = (const float*)d_in[3];
    const float* b2 = (const float*)d_in[4];
    const float* W3 = (const float*)d_in[5];
    const float* b3 = (const float*)d_in[6];
    const float* W4 = (const float*)d_in[7];
    const float* b4 = (const float*)d_in[8];
    float* out = (float*)d_out;

    float* ws = (float*)d_ws;
    float* z       = ws;                        // N*16     = 131072 floats
    float* zT      = ws + N * 16;               // 16*N     = 131072 floats
    float* sqv     = ws + N * 32;               // N        =   8192 floats
    float* partial = ws + N * 32 + N;           // NCHUNK*N = 524288 floats
    // total ws usage: 794624 floats = 3.03 MiB

    encoder_kernel<<<256, 64, 0, stream>>>(x, W1, b1, W2, b2, W3, b3, W4, b4, z, zT, sqv);
    pass1_kernel<<<dim3(16, NCHUNK), 256, 0, stream>>>(z, sqv, partial);
    pass2_kernel<<<N / 4, 256, 0, stream>>>(z, zT, sqv, partial, out);
}